// Round 5
// baseline (2440.747 us; speedup 1.0000x reference)
//
#include <hip/hip_runtime.h>
#include <math.h>

#define TPB 256
#define CAND_CAP 262144u
#define SBCAP 2432     // slots per (group, 256-dst bucket): mean ~2050, +8.4 sigma
#define NGRP 4         // src groups: g = (src*655)>>25  (slices of ~51226 rows = 3.3 MB)
#define BIN_BLOCKS 256

__device__ __forceinline__ float lrelu(float v){ return v >= 0.0f ? v : 0.01f*v; }
__device__ __forceinline__ unsigned fkey(float f){
  unsigned b = __float_as_uint(f);
  return (b & 0x80000000u) ? ~b : (b | 0x80000000u);
}
__device__ __forceinline__ int srcgrp(int s){ return (int)(((unsigned)s * 655u) >> 25); }

// ---------------- gemm1: h1 = x @ W1 (128->16) ----------------
__global__ __launch_bounds__(TPB) void k_gemm1(
    const float* __restrict__ x, const float* __restrict__ W1,
    float* __restrict__ h1, int N)
{
  __shared__ float Ws[2048]; // transposed: Ws[c*128+k]
  for (int idx = threadIdx.x; idx < 2048; idx += TPB){
    int k = idx >> 4, c = idx & 15;
    Ws[c*128 + k] = W1[idx];
  }
  __syncthreads();
  int base = blockIdx.x*(2*TPB) + threadIdx.x;
  int nn[2]; bool val[2];
  #pragma unroll
  for (int j=0;j<2;++j){ nn[j] = base + j*TPB; val[j] = nn[j] < N; }
  float acc[2][16];
  #pragma unroll
  for (int j=0;j<2;++j)
    #pragma unroll
    for (int c=0;c<16;++c) acc[j][c]=0.f;
  for (int k4=0;k4<32;++k4){
    float4 xv[2];
    #pragma unroll
    for (int j=0;j<2;++j)
      xv[j] = val[j] ? ((const float4*)(x + (size_t)nn[j]*128))[k4] : make_float4(0.f,0.f,0.f,0.f);
    #pragma unroll
    for (int c=0;c<16;++c){
      float4 wv = *(const float4*)&Ws[c*128 + k4*4];
      #pragma unroll
      for (int j=0;j<2;++j)
        acc[j][c] += xv[j].x*wv.x + xv[j].y*wv.y + xv[j].z*wv.z + xv[j].w*wv.w;
    }
  }
  #pragma unroll
  for (int j=0;j<2;++j) if (val[j]){
    float4* op = (float4*)(h1 + (size_t)nn[j]*16);
    #pragma unroll
    for (int q=0;q<4;++q)
      op[q] = make_float4(acc[j][q*4+0],acc[j][q*4+1],acc[j][q*4+2],acc[j][q*4+3]);
  }
}

// ---------------- bin edges into (srcgroup, dst>>8) sub-buckets ----------------
// packed: (dst&255)<<24 | src
__global__ __launch_bounds__(TPB) void k_bin(
    const int* __restrict__ src, const int* __restrict__ dst, int E,
    int NB, int* __restrict__ gcur, unsigned* __restrict__ col)
{
  __shared__ int histL[4096];
  int chunk = (E + gridDim.x - 1) / gridDim.x;
  int e0 = blockIdx.x*chunk;
  int e1 = e0 + chunk; if (e1 > E) e1 = E;
  for (int i = threadIdx.x; i < 4096; i += TPB) histL[i] = 0;
  __syncthreads();
  for (int e = e0 + threadIdx.x; e < e1; e += TPB){
    int s = src[e], d = dst[e];
    atomicAdd(&histL[srcgrp(s)*NB + (d>>8)], 1);
  }
  __syncthreads();
  for (int k = threadIdx.x; k < 4096; k += TPB){
    int c = histL[k];
    histL[k] = (c > 0) ? atomicAdd(&gcur[k], c) : 0;
  }
  __syncthreads();
  for (int e = e0 + threadIdx.x; e < e1; e += TPB){
    int s = src[e], d = dst[e];
    int k = srcgrp(s)*NB + (d>>8);
    int slot = atomicAdd(&histL[k], 1);
    if (slot < SBCAP)
      col[(size_t)k*SBCAP + slot] = ((unsigned)(d & 255) << 24) | (unsigned)s;
  }
}

// ---------------- grouped 16-dim aggregation: one launch per src group ----------------
// feat rows for this group's srcs are L2-resident chip-wide during the launch.
__global__ __launch_bounds__(TPB) void k_gagg(
    const float* __restrict__ feat, const unsigned* __restrict__ col,
    const int* __restrict__ gcur, int g, int NB,
    float* __restrict__ agg, int N)
{
  __shared__ float acc[256*17];   // acc[dl*17+ch]: 4 q-lanes of an edge hit 4 distinct banks
  for (int i = threadIdx.x; i < 256*17; i += TPB) acc[i] = 0.f;
  __syncthreads();
  int b = blockIdx.x;
  int sb = g*NB + b;
  int len = gcur[sb]; if (len > SBCAP) len = SBCAP;
  const unsigned* ce = col + (size_t)sb * SBCAP;
  int q = threadIdx.x & 3, le = threadIdx.x >> 2, ch = q*4;
  for (int e0 = 0; e0 < len; e0 += 256){
    int e[4]; unsigned pk[4]; float4 v[4];
    #pragma unroll
    for (int j=0;j<4;++j){
      e[j] = e0 + j*64 + le;
      int idx = e[j] < len ? e[j] : len-1;
      pk[j] = ce[idx];
    }
    #pragma unroll
    for (int j=0;j<4;++j){
      int s = (int)(pk[j] & 0xFFFFFFu);
      v[j] = ((const float4*)(feat + (size_t)s*16))[q];
    }
    #pragma unroll
    for (int j=0;j<4;++j){
      if (e[j] < len){
        int dl = (int)(pk[j] >> 24);
        atomicAdd(&acc[dl*17+ch+0], v[j].x);
        atomicAdd(&acc[dl*17+ch+1], v[j].y);
        atomicAdd(&acc[dl*17+ch+2], v[j].z);
        atomicAdd(&acc[dl*17+ch+3], v[j].w);
      }
    }
  }
  __syncthreads();
  if (len > 0){
    for (int d0 = 0; d0 < 256; d0 += 64){
      int dl = d0 + le;
      int d = b*256 + dl;
      if (d < N){
        float* ap = agg + (size_t)d*16 + ch;
        atomicAdd(ap+0, acc[dl*17+ch+0]);
        atomicAdd(ap+1, acc[dl*17+ch+1]);
        atomicAdd(ap+2, acc[dl*17+ch+2]);
        atomicAdd(ap+3, acc[dl*17+ch+3]);
      }
    }
  }
}

// ---------------- per-channel sum/sumsq over a [N][16] array ----------------
__global__ __launch_bounds__(TPB) void k_stats16(
    const float* __restrict__ a, float* __restrict__ stats, int N)
{
  __shared__ float red[TPB][17];
  int i = blockIdx.x*TPB + threadIdx.x;
  float v[16];
  if (i < N){
    const float4* ap = (const float4*)(a + (size_t)i*16);
    float4 r0=ap[0], r1=ap[1], r2=ap[2], r3=ap[3];
    v[0]=r0.x; v[1]=r0.y; v[2]=r0.z; v[3]=r0.w;
    v[4]=r1.x; v[5]=r1.y; v[6]=r1.z; v[7]=r1.w;
    v[8]=r2.x; v[9]=r2.y; v[10]=r2.z; v[11]=r2.w;
    v[12]=r3.x; v[13]=r3.y; v[14]=r3.z; v[15]=r3.w;
  } else {
    #pragma unroll
    for (int c=0;c<16;++c) v[c]=0.f;
  }
  #pragma unroll
  for (int c=0;c<16;++c) red[threadIdx.x][c]=v[c];
  __syncthreads();
  if (threadIdx.x < 32){
    int c = threadIdx.x & 15, r0 = (threadIdx.x>>4)*128;
    float sm=0.f, qs=0.f;
    for (int r=0;r<128;++r){ float vv = red[r0+r][c]; sm+=vv; qs+=vv*vv; }
    atomicAdd(&stats[c], sm);
    atomicAdd(&stats[16+c], qs);
  }
}

// ---------------- BN1 + lrelu (in place) + p1 = h.Wrel, s1 = h.Wroot + br ----------------
__global__ __launch_bounds__(TPB) void k_bn1(
    float* __restrict__ h, const float* __restrict__ stats,
    const float* __restrict__ g, const float* __restrict__ be,
    const float* __restrict__ Wr, const float* __restrict__ br,
    const float* __restrict__ Wroot,
    float* __restrict__ p, float* __restrict__ s, int N, float invn)
{
  int i = blockIdx.x*TPB + threadIdx.x;
  if (i >= N) return;
  float* hp = h + (size_t)i*16;
  float pv=0.f, rv=0.f;
  #pragma unroll
  for (int c=0;c<16;++c){
    float mu = stats[c]*invn;
    float var = stats[16+c]*invn - mu*mu;
    float rsd = 1.0f / sqrtf(var + 1e-5f);
    float v = (hp[c]-mu)*rsd*g[c] + be[c];
    v = lrelu(v);
    hp[c] = v;
    pv += v*Wr[c];
    rv += v*Wroot[c];
  }
  p[i] = pv;
  s[i] = rv + br[0];
}

// ---------------- score aggregation over all groups: s[d] += sum p[src] ----------------
// layer 2 needs no mask: bn2 zeroes p for dropped nodes; dropped dst rows masked later.
__global__ __launch_bounds__(TPB) void k_score(
    const float* __restrict__ p, const unsigned* __restrict__ col,
    const int* __restrict__ gcur, int NB, float* __restrict__ s, int N)
{
  __shared__ float sacc[256];
  int b = blockIdx.x;
  sacc[threadIdx.x] = 0.f;
  __syncthreads();
  for (int g = 0; g < NGRP; ++g){
    int sb = g*NB + b;
    int len = gcur[sb]; if (len > SBCAP) len = SBCAP;
    const unsigned* ce = col + (size_t)sb * SBCAP;
    for (int e0 = threadIdx.x*8; e0 < len; e0 += TPB*8){
      uint4 u0 = *(const uint4*)(ce + e0);
      uint4 u1 = *(const uint4*)(ce + e0 + 4);
      unsigned pk[8] = {u0.x,u0.y,u0.z,u0.w,u1.x,u1.y,u1.z,u1.w};
      int cnt = len - e0; // >= 1
      float pv[8];
      #pragma unroll
      for (int j=0;j<8;++j){
        int si = (int)(pk[j] & 0xFFFFFFu);
        if (si >= N) si = 0;   // stale-slot guard beyond len
        pv[j] = p[si];
      }
      #pragma unroll
      for (int j=0;j<8;++j)
        if (j < cnt) atomicAdd(&sacc[pk[j] >> 24], pv[j]);
    }
  }
  __syncthreads();
  int d = b*256 + threadIdx.x;
  if (d < N) s[d] += sacc[threadIdx.x];
}

// ---------------- radix-select stage 1: monotonic keys + top-16-bit histogram ----------------
__global__ __launch_bounds__(TPB) void k_keyhist(
    const float* __restrict__ s, const unsigned char* __restrict__ keep,
    unsigned* __restrict__ ukey, unsigned* __restrict__ hist, int N)
{
  int i = blockIdx.x*TPB + threadIdx.x;
  if (i >= N) return;
  unsigned u = 0u;
  if (!keep || keep[i]) u = fkey(s[i]);
  ukey[i] = u;
  if (u) atomicAdd(&hist[u>>16], 1u);
}

// ---------------- find threshold bucket (1 block) ----------------
__global__ __launch_bounds__(TPB) void k_findbucket(
    const unsigned* __restrict__ hist, unsigned k, unsigned* __restrict__ ctrl)
{
  __shared__ unsigned seg[TPB];
  __shared__ unsigned hb[256];
  __shared__ unsigned sS, scum;
  unsigned t = threadIdx.x;
  const uint4* h4 = (const uint4*)hist;
  unsigned ssum = 0;
  for (int q=0;q<64;++q){
    uint4 v = h4[t*64 + q];
    ssum += v.x + v.y + v.z + v.w;
  }
  seg[t] = ssum;
  __syncthreads();
  if (t == 0){
    unsigned cum = 0, S = 255;
    for (int s2=255; s2>=0; --s2){
      if (cum + seg[s2] >= k){ S = (unsigned)s2; break; }
      cum += seg[s2];
    }
    sS = S; scum = cum;
  }
  __syncthreads();
  hb[t] = hist[sS*256 + t];
  __syncthreads();
  if (t == 0){
    unsigned cum = scum, B = 0, need = 0;
    for (int b=255;b>=0;--b){
      unsigned h = hb[b];
      if (cum + h >= k){ B = sS*256 + (unsigned)b; need = k - cum; break; }
      cum += h;
    }
    ctrl[1] = B;
    ctrl[2] = need;
  }
}

// ---------------- collect boundary-bucket candidates; also re-zero hist for next use --------
__global__ __launch_bounds__(TPB) void k_collect(
    const unsigned* __restrict__ ukey, unsigned* __restrict__ cand,
    unsigned* __restrict__ ctrl, unsigned* __restrict__ hist, int N)
{
  int i = blockIdx.x*TPB + threadIdx.x;
  if (i < 65536) hist[i] = 0u;
  if (i < N){
    unsigned u = ukey[i];
    if ((u>>16) == ctrl[1]){
      unsigned pos = atomicAdd(&ctrl[6], 1u);
      if (pos < CAND_CAP) cand[pos] = u;
    }
  }
}

// ---------------- refine low 16 bits (1 block) -> T, needT; resets tie & cand counters ------
__global__ __launch_bounds__(TPB) void k_refine(
    const unsigned* __restrict__ cand, unsigned* __restrict__ ctrl)
{
  __shared__ unsigned h8[256];
  __shared__ unsigned sB2, sN2;
  unsigned t = threadIdx.x;
  unsigned L = ctrl[6];
  unsigned need = ctrl[2];
  h8[t] = 0u; __syncthreads();
  for (unsigned i=t; i<L; i+=TPB) atomicAdd(&h8[(cand[i]>>8)&0xFFu], 1u);
  __syncthreads();
  if (t == 0){
    unsigned cum=0, B2=0, n2=need;
    for (int b=255;b>=0;--b){
      unsigned h = h8[b];
      if (cum + h >= need){ B2=(unsigned)b; n2 = need - cum; break; }
      cum += h;
    }
    sB2 = B2; sN2 = n2;
  }
  __syncthreads();
  unsigned B2 = sB2, need2 = sN2;
  h8[t] = 0u; __syncthreads();
  for (unsigned i=t; i<L; i+=TPB){
    unsigned u = cand[i];
    if (((u>>8)&0xFFu) == B2) atomicAdd(&h8[u&0xFFu], 1u);
  }
  __syncthreads();
  if (t == 0){
    unsigned cum=0, B3=0, n3=need2;
    for (int b=255;b>=0;--b){
      unsigned h = h8[b];
      if (cum + h >= need2){ B3=(unsigned)b; n3 = need2 - cum; break; }
      cum += h;
    }
    unsigned B = ctrl[1];
    ctrl[3] = (B<<16) | (B2<<8) | B3; // threshold key T
    ctrl[4] = n3;                    // how many ==T to take
    ctrl[5] = 0u;                    // tie counter
    ctrl[6] = 0u;                    // cand counter (for next selection)
  }
}

// ---------------- mark keep1 + z1 = keep ? h1p * tanh(s1) : 0 ----------------
__global__ __launch_bounds__(TPB) void k_mark1(
    const unsigned* __restrict__ ukey, const float* __restrict__ s1,
    const float* __restrict__ h1p, float* __restrict__ z1,
    unsigned char* __restrict__ keep, unsigned* __restrict__ ctrl, int N)
{
  int i = blockIdx.x*TPB + threadIdx.x;
  if (i >= N) return;
  unsigned u = ukey[i], T = ctrl[3], needT = ctrl[4];
  bool sel = u > T;
  if (!sel && u == T) sel = (atomicAdd(&ctrl[5], 1u) < needT);
  keep[i] = sel ? (unsigned char)1 : (unsigned char)0;
  float tv = sel ? tanhf(s1[i]) : 0.0f;
  const float4* hp = (const float4*)(h1p + (size_t)i*16);
  float4* zp = (float4*)(z1 + (size_t)i*16);
  #pragma unroll
  for (int q=0;q<4;++q){
    float4 v = hp[q];
    zp[q] = make_float4(v.x*tv, v.y*tv, v.z*tv, v.w*tv);
  }
}

// ---------------- conv2 epilogue: GEMM 16->32 per kept node + BN stats ----------------
__global__ __launch_bounds__(TPB) void k_conv2post(
    const float* __restrict__ agg2, const unsigned char* __restrict__ keep,
    const float* __restrict__ W2, float* __restrict__ h2, int N,
    float* __restrict__ stats)
{
  __shared__ float W2s[512];
  __shared__ float red[TPB][33];
  for (int i = threadIdx.x; i < 512; i += TPB) W2s[i] = W2[i];
  __syncthreads();
  int i = blockIdx.x*TPB + threadIdx.x;
  float h[32];
  #pragma unroll
  for (int c2=0;c2<32;++c2) h[c2]=0.f;
  bool act = (i < N) && keep[i];
  if (act){
    const float4* ap = (const float4*)(agg2 + (size_t)i*16);
    float4 r0=ap[0], r1=ap[1], r2=ap[2], r3=ap[3];
    float a[16] = {r0.x,r0.y,r0.z,r0.w, r1.x,r1.y,r1.z,r1.w,
                   r2.x,r2.y,r2.z,r2.w, r3.x,r3.y,r3.z,r3.w};
    #pragma unroll
    for (int c=0;c<16;++c){
      float av = a[c];
      const float* wrow = &W2s[c*32];
      #pragma unroll
      for (int c2=0;c2<32;++c2) h[c2] += av*wrow[c2];
    }
    float4* op = (float4*)(h2 + (size_t)i*32);
    #pragma unroll
    for (int q=0;q<8;++q)
      op[q] = make_float4(h[q*4+0],h[q*4+1],h[q*4+2],h[q*4+3]);
  }
  #pragma unroll
  for (int c2=0;c2<32;++c2) red[threadIdx.x][c2]=h[c2];
  __syncthreads();
  if (threadIdx.x < 64){
    int c = threadIdx.x & 31, r0 = (threadIdx.x>>5)*128;
    float sm=0.f, qs=0.f;
    for (int r=0;r<128;++r){ float v = red[r0+r][c]; sm+=v; qs+=v*v; }
    atomicAdd(&stats[c], sm);
    atomicAdd(&stats[32+c], qs);
  }
}

// ---------------- BN2 + lrelu (kept rows) + p2, s2; zero p/s for dropped ----------------
__global__ __launch_bounds__(TPB) void k_bn2(
    float* __restrict__ h, const float* __restrict__ stats,
    const float* __restrict__ g, const float* __restrict__ be,
    const float* __restrict__ Wr, const float* __restrict__ br,
    const float* __restrict__ Wroot, const unsigned char* __restrict__ keep,
    float* __restrict__ p, float* __restrict__ s, int N, float invn)
{
  int i = blockIdx.x*TPB + threadIdx.x;
  if (i >= N) return;
  if (!keep[i]){ p[i] = 0.f; s[i] = 0.f; return; }
  float* hp = h + (size_t)i*32;
  float pv=0.f, rv=0.f;
  #pragma unroll
  for (int c=0;c<32;++c){
    float mu = stats[c]*invn;
    float var = stats[32+c]*invn - mu*mu;
    float rsd = 1.0f / sqrtf(var + 1e-5f);
    float v = (hp[c]-mu)*rsd*g[c] + be[c];
    v = lrelu(v);
    hp[c] = v;
    pv += v*Wr[c];
    rv += v*Wroot[c];
  }
  p[i] = pv;
  s[i] = rv + br[0];
}

// ---------------- final: select top-k2, pooled += h2p * tanh(s2) ----------------
__global__ __launch_bounds__(TPB) void k_final(
    const unsigned* __restrict__ ukey, const float* __restrict__ s2,
    const float* __restrict__ h2p, unsigned* __restrict__ ctrl,
    float* __restrict__ pooled, int N)
{
  __shared__ float red[TPB][33];
  int i = blockIdx.x*TPB + threadIdx.x;
  float contrib[32];
  #pragma unroll
  for (int c=0;c<32;++c) contrib[c]=0.f;
  if (i < N){
    unsigned u = ukey[i], T = ctrl[3], needT = ctrl[4];
    bool sel = u > T;
    if (!sel && u == T) sel = (atomicAdd(&ctrl[5], 1u) < needT);
    if (sel){
      float tv = tanhf(s2[i]);
      const float* hp = h2p + (size_t)i*32;
      #pragma unroll
      for (int c=0;c<32;++c) contrib[c] = hp[c]*tv;
    }
  }
  #pragma unroll
  for (int c=0;c<32;++c) red[threadIdx.x][c]=contrib[c];
  __syncthreads();
  if (threadIdx.x < 64){
    int c = threadIdx.x & 31, r0 = (threadIdx.x>>5)*128;
    float sm=0.f;
    for (int r=0;r<128;++r) sm += red[r0+r][c];
    atomicAdd(&pooled[c], sm);
  }
}

// ---------------- tiny MLP 32->8->4->2 ----------------
__global__ void k_mlp(const float* __restrict__ pooled,
    const float* __restrict__ fw1, const float* __restrict__ fb1,
    const float* __restrict__ fw2, const float* __restrict__ fb2,
    const float* __restrict__ fw3, const float* __restrict__ fb3,
    float* __restrict__ out)
{
  if (blockIdx.x==0 && threadIdx.x==0){
    float a[8];
    for (int o=0;o<8;++o){
      float t = fb1[o];
      for (int c=0;c<32;++c) t += pooled[c]*fw1[c*8+o];
      a[o] = lrelu(t);
    }
    float b[4];
    for (int o=0;o<4;++o){
      float t = fb2[o];
      for (int c=0;c<8;++c) t += a[c]*fw2[c*4+o];
      b[o] = lrelu(t);
    }
    for (int o=0;o<2;++o){
      float t = fb3[o];
      for (int c=0;c<4;++c) t += b[c]*fw3[c*2+o];
      out[o] = lrelu(t);
    }
  }
}

extern "C" void kernel_launch(void* const* d_in, const int* in_sizes, int n_in,
                              void* d_out, int out_size, void* d_ws, size_t ws_size,
                              hipStream_t stream)
{
  const float* x      = (const float*)d_in[0];
  const int*   ei     = (const int*)  d_in[1];
  // d_in[2] edge_weigth, d_in[3] batch: unused by the reference math
  const float* W1     = (const float*)d_in[4];
  const float* g1     = (const float*)d_in[6];
  const float* be1    = (const float*)d_in[7];
  const float* Wr1    = (const float*)d_in[8];
  const float* br1    = (const float*)d_in[9];
  const float* Wroot1 = (const float*)d_in[10];
  const float* W2     = (const float*)d_in[11];
  const float* g2     = (const float*)d_in[13];
  const float* be2    = (const float*)d_in[14];
  const float* Wr2    = (const float*)d_in[15];
  const float* br2    = (const float*)d_in[16];
  const float* Wroot2 = (const float*)d_in[17];
  const float* fw1    = (const float*)d_in[18];
  const float* fb1    = (const float*)d_in[19];
  const float* fw2    = (const float*)d_in[20];
  const float* fb2    = (const float*)d_in[21];
  const float* fw3    = (const float*)d_in[22];
  const float* fb3    = (const float*)d_in[23];

  int N = in_sizes[0] / 128;
  int E = in_sizes[1] / 2;
  const int* srcp = ei;
  const int* dstp = ei + E;
  int k1 = (N + 1) / 2;
  int k2 = (k1 + 1) / 2;
  int NB  = (N + 255) >> 8;           // 256-dst buckets (<= 1024)
  int nbN = (N + TPB - 1) / TPB;

  char* w = (char*)d_ws;
  size_t off = 0;
  auto alloc = [&](size_t bytes)->char* {
    char* ptr = w + off;
    off += (bytes + 255) & ~(size_t)255;
    return ptr;
  };
  // --- zeroed prefix: gcur | hist | ctrl(+stats+pooled) | agg1 | agg2 ---
  int*      gcur = (int*)     alloc(4096*4);
  unsigned* hist = (unsigned*)alloc(65536*4);
  unsigned* ctrl = (unsigned*)alloc(1024);
  float*    agg1 = (float*)   alloc((size_t)N*16*4); // later h1p (bn1 in place)
  float*    agg2 = (float*)   alloc((size_t)N*16*4);
  size_t zerosz = off;
  float* stats1 = (float*)(ctrl + 32);   // 32 floats
  float* stats2 = (float*)(ctrl + 96);   // 64 floats
  float* pooled = (float*)(ctrl + 160);  // 32 floats
  // --- rest of workspace ---
  unsigned* col  = (unsigned*)alloc((size_t)NGRP*NB*SBCAP*4);
  float*    h1   = (float*)   alloc((size_t)N*16*4); // later reused as z1
  float*    h2   = (float*)   alloc((size_t)N*32*4); // later h2p (in place)
  float*    sbuf = (float*)   alloc((size_t)N*4);    // s1 then s2
  float*    pbuf = (float*)   alloc((size_t)N*4);    // p1 then p2
  unsigned* ukey = (unsigned*)alloc((size_t)N*4);
  unsigned char* keep = (unsigned char*)alloc((size_t)N);
  unsigned* cand = (unsigned*)alloc((size_t)CAND_CAP*4);
  (void)ws_size; (void)n_in; (void)out_size;

  hipMemsetAsync(d_ws, 0, zerosz, stream);

  // layer 1
  k_gemm1     <<<(N + 2*TPB - 1)/(2*TPB), TPB, 0, stream>>>(x, W1, h1, N);
  k_bin       <<<BIN_BLOCKS, TPB, 0, stream>>>(srcp, dstp, E, NB, gcur, col);
  for (int g = 0; g < NGRP; ++g)  // sequential launches = hard global phase sync
    k_gagg    <<<NB, TPB, 0, stream>>>(h1, col, gcur, g, NB, agg1, N);
  k_stats16   <<<nbN, TPB, 0, stream>>>(agg1, stats1, N);
  k_bn1       <<<nbN, TPB, 0, stream>>>(agg1, stats1, g1, be1, Wr1, br1, Wroot1,
                                        pbuf, sbuf, N, 1.0f/(float)N);
  k_score     <<<NB, TPB, 0, stream>>>(pbuf, col, gcur, NB, sbuf, N);
  // SAG pool 1 (radix select k1)
  k_keyhist   <<<nbN, TPB, 0, stream>>>(sbuf, nullptr, ukey, hist, N);
  k_findbucket<<<1, TPB, 0, stream>>>(hist, (unsigned)k1, ctrl);
  k_collect   <<<nbN, TPB, 0, stream>>>(ukey, cand, ctrl, hist, N);
  k_refine    <<<1, TPB, 0, stream>>>(cand, ctrl);
  k_mark1     <<<nbN, TPB, 0, stream>>>(ukey, sbuf, agg1, h1, keep, ctrl, N);
  // layer 2 (z1 rows of dropped nodes are exact zeros -> unconditional gathers)
  for (int g = 0; g < NGRP; ++g)
    k_gagg    <<<NB, TPB, 0, stream>>>(h1, col, gcur, g, NB, agg2, N);
  k_conv2post <<<nbN, TPB, 0, stream>>>(agg2, keep, W2, h2, N, stats2);
  k_bn2       <<<nbN, TPB, 0, stream>>>(h2, stats2, g2, be2, Wr2, br2, Wroot2, keep,
                                        pbuf, sbuf, N, 1.0f/(float)k1);
  k_score     <<<NB, TPB, 0, stream>>>(pbuf, col, gcur, NB, sbuf, N);
  // SAG pool 2 (radix select k2) + global pool
  k_keyhist   <<<nbN, TPB, 0, stream>>>(sbuf, keep, ukey, hist, N);
  k_findbucket<<<1, TPB, 0, stream>>>(hist, (unsigned)k2, ctrl);
  k_collect   <<<nbN, TPB, 0, stream>>>(ukey, cand, ctrl, hist, N);
  k_refine    <<<1, TPB, 0, stream>>>(cand, ctrl);
  k_final     <<<nbN, TPB, 0, stream>>>(ukey, sbuf, h2, ctrl, pooled, N);
  k_mlp       <<<1, 64, 0, stream>>>(pooled, fw1, fb1, fw2, fb2, fw3, fb3, (float*)d_out);
}

// Round 6
// 2220.927 us; speedup vs baseline: 1.0990x; 1.0990x over previous
//
#include <hip/hip_runtime.h>
#include <math.h>

#define TPB 256
#define CAND_CAP 262144u
#define BCAP 9216      // slots per 256-dst bucket: mean 8184, +11 sigma (mult of 8)
#define SPLIT 2        // blocks per bucket in gather kernels
#define BIN_BLOCKS 512

__device__ __forceinline__ float lrelu(float v){ return v >= 0.0f ? v : 0.01f*v; }
__device__ __forceinline__ unsigned fkey(float f){
  unsigned b = __float_as_uint(f);
  return (b & 0x80000000u) ? ~b : (b | 0x80000000u);
}

// ---------------- gemm1: h1 = x @ W1 (128->16) ----------------
__global__ __launch_bounds__(TPB) void k_gemm1(
    const float* __restrict__ x, const float* __restrict__ W1,
    float* __restrict__ h1, int N)
{
  __shared__ float Ws[2048]; // transposed: Ws[c*128+k]
  for (int idx = threadIdx.x; idx < 2048; idx += TPB){
    int k = idx >> 4, c = idx & 15;
    Ws[c*128 + k] = W1[idx];
  }
  __syncthreads();
  int base = blockIdx.x*(2*TPB) + threadIdx.x;
  int nn[2]; bool val[2];
  #pragma unroll
  for (int j=0;j<2;++j){ nn[j] = base + j*TPB; val[j] = nn[j] < N; }
  float acc[2][16];
  #pragma unroll
  for (int j=0;j<2;++j)
    #pragma unroll
    for (int c=0;c<16;++c) acc[j][c]=0.f;
  for (int k4=0;k4<32;++k4){
    float4 xv[2];
    #pragma unroll
    for (int j=0;j<2;++j)
      xv[j] = val[j] ? ((const float4*)(x + (size_t)nn[j]*128))[k4] : make_float4(0.f,0.f,0.f,0.f);
    #pragma unroll
    for (int c=0;c<16;++c){
      float4 wv = *(const float4*)&Ws[c*128 + k4*4];
      #pragma unroll
      for (int j=0;j<2;++j)
        acc[j][c] += xv[j].x*wv.x + xv[j].y*wv.y + xv[j].z*wv.z + xv[j].w*wv.w;
    }
  }
  #pragma unroll
  for (int j=0;j<2;++j) if (val[j]){
    float4* op = (float4*)(h1 + (size_t)nn[j]*16);
    #pragma unroll
    for (int q=0;q<4;++q)
      op[q] = make_float4(acc[j][q*4+0],acc[j][q*4+1],acc[j][q*4+2],acc[j][q*4+3]);
  }
}

// ---------------- bin edges into 256-dst buckets, packed (dst&255)<<24 | src ----------
__global__ __launch_bounds__(TPB) void k_bin(
    const int* __restrict__ src, const int* __restrict__ dst, int E,
    int NB, int* __restrict__ gcur, unsigned* __restrict__ col)
{
  __shared__ int histL[1024];
  int chunk = (E + gridDim.x - 1) / gridDim.x;
  int e0 = blockIdx.x*chunk;
  int e1 = e0 + chunk; if (e1 > E) e1 = E;
  for (int i = threadIdx.x; i < 1024; i += TPB) histL[i] = 0;
  __syncthreads();
  for (int e = e0 + threadIdx.x; e < e1; e += TPB)
    atomicAdd(&histL[dst[e] >> 8], 1);
  __syncthreads();
  for (int b = threadIdx.x; b < 1024; b += TPB){
    int c = histL[b];
    histL[b] = (c > 0) ? atomicAdd(&gcur[b], c) : 0;
  }
  __syncthreads();
  for (int e = e0 + threadIdx.x; e < e1; e += TPB){
    int d = dst[e];
    int b = d >> 8;
    int slot = atomicAdd(&histL[b], 1);
    if (slot < BCAP)
      col[(size_t)b*BCAP + slot] = ((unsigned)(d & 255) << 24) | (unsigned)src[e];
  }
}

// ---------------- gather-aggregate: SPLIT blocks/bucket, 8-deep batched gathers ----------
// partial[s] rows owned exclusively by split s -> plain stores, no atomics, no pre-zero.
__global__ __launch_bounds__(TPB) void k_gagg(
    const float* __restrict__ feat, const unsigned* __restrict__ col,
    const int* __restrict__ gcur, float* __restrict__ partial, int N)
{
  __shared__ float acc[256*17];   // acc[dl*17+ch]
  int b = blockIdx.x >> 1;
  int s = blockIdx.x & 1;
  for (int i = threadIdx.x; i < 256*17; i += TPB) acc[i] = 0.f;
  __syncthreads();
  int len = gcur[b]; if (len > BCAP) len = BCAP;
  int ch = (len + 1) >> 1;
  int e0b = s*ch;
  int e1b = e0b + ch; if (e1b > len) e1b = len;
  const unsigned* ce = col + (size_t)b*BCAP;
  int q = threadIdx.x & 3, le = threadIdx.x >> 2, c0 = q*4;
  for (int e0 = e0b; e0 < e1b; e0 += 512){
    int e[8]; unsigned pk[8]; float4 v[8];
    #pragma unroll
    for (int j=0;j<8;++j){
      e[j] = e0 + j*64 + le;
      pk[j] = ce[e[j] < e1b ? e[j] : e1b-1];
    }
    #pragma unroll
    for (int j=0;j<8;++j)
      v[j] = ((const float4*)(feat + (size_t)(pk[j] & 0xFFFFFFu)*16))[q];
    #pragma unroll
    for (int j=0;j<8;++j){
      if (e[j] < e1b){
        int dl = (int)(pk[j] >> 24);
        atomicAdd(&acc[dl*17+c0+0], v[j].x);
        atomicAdd(&acc[dl*17+c0+1], v[j].y);
        atomicAdd(&acc[dl*17+c0+2], v[j].z);
        atomicAdd(&acc[dl*17+c0+3], v[j].w);
      }
    }
  }
  __syncthreads();
  int t = threadIdx.x;
  int d = b*256 + t;
  if (d < N){
    float4* pp = (float4*)(partial + ((size_t)s*N + d)*16);
    #pragma unroll
    for (int k=0;k<4;++k)
      pp[k] = make_float4(acc[t*17+k*4+0], acc[t*17+k*4+1],
                          acc[t*17+k*4+2], acc[t*17+k*4+3]);
  }
}

// ---------------- reduce partials -> agg1 + BN stats ----------------
__global__ __launch_bounds__(TPB) void k_red1(
    const float* __restrict__ partial, float* __restrict__ agg,
    float* __restrict__ stats, int N)
{
  __shared__ float red[TPB][17];
  int i = blockIdx.x*TPB + threadIdx.x;
  float v[16];
  if (i < N){
    const float4* p0 = (const float4*)(partial + (size_t)i*16);
    const float4* p1 = (const float4*)(partial + ((size_t)N + i)*16);
    float4* op = (float4*)(agg + (size_t)i*16);
    #pragma unroll
    for (int k=0;k<4;++k){
      float4 a = p0[k], bq = p1[k];
      float4 r = make_float4(a.x+bq.x, a.y+bq.y, a.z+bq.z, a.w+bq.w);
      op[k] = r;
      v[k*4+0]=r.x; v[k*4+1]=r.y; v[k*4+2]=r.z; v[k*4+3]=r.w;
    }
  } else {
    #pragma unroll
    for (int c=0;c<16;++c) v[c]=0.f;
  }
  #pragma unroll
  for (int c=0;c<16;++c) red[threadIdx.x][c]=v[c];
  __syncthreads();
  if (threadIdx.x < 32){
    int c = threadIdx.x & 15, r0 = (threadIdx.x>>4)*128;
    float sm=0.f, qs=0.f;
    for (int r=0;r<128;++r){ float vv = red[r0+r][c]; sm+=vv; qs+=vv*vv; }
    atomicAdd(&stats[c], sm);
    atomicAdd(&stats[16+c], qs);
  }
}

// ---------------- BN1 + lrelu (in place) + p1 = h.Wrel, s1 = h.Wroot + br ----------------
__global__ __launch_bounds__(TPB) void k_bn1(
    float* __restrict__ h, const float* __restrict__ stats,
    const float* __restrict__ g, const float* __restrict__ be,
    const float* __restrict__ Wr, const float* __restrict__ br,
    const float* __restrict__ Wroot,
    float* __restrict__ p, float* __restrict__ s, int N, float invn)
{
  int i = blockIdx.x*TPB + threadIdx.x;
  if (i >= N) return;
  float* hp = h + (size_t)i*16;
  float pv=0.f, rv=0.f;
  #pragma unroll
  for (int c=0;c<16;++c){
    float mu = stats[c]*invn;
    float var = stats[16+c]*invn - mu*mu;
    float rsd = 1.0f / sqrtf(var + 1e-5f);
    float v = (hp[c]-mu)*rsd*g[c] + be[c];
    v = lrelu(v);
    hp[c] = v;
    pv += v*Wr[c];
    rv += v*Wroot[c];
  }
  p[i] = pv;
  s[i] = rv + br[0];
}

// ---------------- score aggregation: SPLIT blocks/bucket, 8-batched, atomic flush ---------
// layer 2 needs no mask: bn2 zeroes p for dropped nodes; dropped dst rows masked at keyhist.
__global__ __launch_bounds__(TPB) void k_score(
    const float* __restrict__ p, const unsigned* __restrict__ col,
    const int* __restrict__ gcur, float* __restrict__ s, int N)
{
  __shared__ float sacc[256];
  int b = blockIdx.x >> 1;
  int sp = blockIdx.x & 1;
  sacc[threadIdx.x] = 0.f;
  __syncthreads();
  int len = gcur[b]; if (len > BCAP) len = BCAP;
  int ch = (((len + 1) >> 1) + 7) & ~7;
  int e0b = sp*ch;
  int e1b = e0b + ch; if (e1b > len) e1b = len;
  const unsigned* ce = col + (size_t)b*BCAP;
  for (int e0 = e0b + threadIdx.x*8; e0 < e1b; e0 += TPB*8){
    uint4 u0 = *(const uint4*)(ce + e0);
    uint4 u1 = *(const uint4*)(ce + e0 + 4);
    unsigned pk[8] = {u0.x,u0.y,u0.z,u0.w,u1.x,u1.y,u1.z,u1.w};
    int cnt = e1b - e0; // >= 1
    float pv[8];
    #pragma unroll
    for (int j=0;j<8;++j){
      int si = (int)(pk[j] & 0xFFFFFFu);
      if (si >= N) si = 0;   // stale-slot guard beyond len
      pv[j] = p[si];
    }
    #pragma unroll
    for (int j=0;j<8;++j)
      if (j < cnt) atomicAdd(&sacc[pk[j] >> 24], pv[j]);
  }
  __syncthreads();
  int d = b*256 + threadIdx.x;
  if (d < N && sacc[threadIdx.x] != 0.f) atomicAdd(&s[d], sacc[threadIdx.x]);
}

// ---------------- radix-select stage 1: monotonic keys + top-16-bit histogram ----------------
__global__ __launch_bounds__(TPB) void k_keyhist(
    const float* __restrict__ s, const unsigned char* __restrict__ keep,
    unsigned* __restrict__ ukey, unsigned* __restrict__ hist, int N)
{
  int i = blockIdx.x*TPB + threadIdx.x;
  if (i >= N) return;
  unsigned u = 0u;
  if (!keep || keep[i]) u = fkey(s[i]);
  ukey[i] = u;
  if (u) atomicAdd(&hist[u>>16], 1u);
}

// ---------------- find threshold bucket (1 block) ----------------
__global__ __launch_bounds__(TPB) void k_findbucket(
    const unsigned* __restrict__ hist, unsigned k, unsigned* __restrict__ ctrl)
{
  __shared__ unsigned seg[TPB];
  __shared__ unsigned hb[256];
  __shared__ unsigned sS, scum;
  unsigned t = threadIdx.x;
  const uint4* h4 = (const uint4*)hist;
  unsigned ssum = 0;
  for (int q=0;q<64;++q){
    uint4 v = h4[t*64 + q];
    ssum += v.x + v.y + v.z + v.w;
  }
  seg[t] = ssum;
  __syncthreads();
  if (t == 0){
    unsigned cum = 0, S = 255;
    for (int s2=255; s2>=0; --s2){
      if (cum + seg[s2] >= k){ S = (unsigned)s2; break; }
      cum += seg[s2];
    }
    sS = S; scum = cum;
  }
  __syncthreads();
  hb[t] = hist[sS*256 + t];
  __syncthreads();
  if (t == 0){
    unsigned cum = scum, B = 0, need = 0;
    for (int b=255;b>=0;--b){
      unsigned h = hb[b];
      if (cum + h >= k){ B = sS*256 + (unsigned)b; need = k - cum; break; }
      cum += h;
    }
    ctrl[1] = B;
    ctrl[2] = need;
  }
}

// ---------------- collect boundary-bucket candidates; also re-zero hist for next use --------
__global__ __launch_bounds__(TPB) void k_collect(
    const unsigned* __restrict__ ukey, unsigned* __restrict__ cand,
    unsigned* __restrict__ ctrl, unsigned* __restrict__ hist, int N)
{
  int i = blockIdx.x*TPB + threadIdx.x;
  if (i < 65536) hist[i] = 0u;
  if (i < N){
    unsigned u = ukey[i];
    if ((u>>16) == ctrl[1]){
      unsigned pos = atomicAdd(&ctrl[6], 1u);
      if (pos < CAND_CAP) cand[pos] = u;
    }
  }
}

// ---------------- refine low 16 bits (1 block) -> T, needT; resets tie & cand counters ------
__global__ __launch_bounds__(TPB) void k_refine(
    const unsigned* __restrict__ cand, unsigned* __restrict__ ctrl)
{
  __shared__ unsigned h8[256];
  __shared__ unsigned sB2, sN2;
  unsigned t = threadIdx.x;
  unsigned L = ctrl[6];
  unsigned need = ctrl[2];
  h8[t] = 0u; __syncthreads();
  for (unsigned i=t; i<L; i+=TPB) atomicAdd(&h8[(cand[i]>>8)&0xFFu], 1u);
  __syncthreads();
  if (t == 0){
    unsigned cum=0, B2=0, n2=need;
    for (int b=255;b>=0;--b){
      unsigned h = h8[b];
      if (cum + h >= need){ B2=(unsigned)b; n2 = need - cum; break; }
      cum += h;
    }
    sB2 = B2; sN2 = n2;
  }
  __syncthreads();
  unsigned B2 = sB2, need2 = sN2;
  h8[t] = 0u; __syncthreads();
  for (unsigned i=t; i<L; i+=TPB){
    unsigned u = cand[i];
    if (((u>>8)&0xFFu) == B2) atomicAdd(&h8[u&0xFFu], 1u);
  }
  __syncthreads();
  if (t == 0){
    unsigned cum=0, B3=0, n3=need2;
    for (int b=255;b>=0;--b){
      unsigned h = h8[b];
      if (cum + h >= need2){ B3=(unsigned)b; n3 = need2 - cum; break; }
      cum += h;
    }
    unsigned B = ctrl[1];
    ctrl[3] = (B<<16) | (B2<<8) | B3; // threshold key T
    ctrl[4] = n3;                    // how many ==T to take
    ctrl[5] = 0u;                    // tie counter
    ctrl[6] = 0u;                    // cand counter (for next selection)
  }
}

// ---------------- mark keep1 + z1 = keep ? h1p * tanh(s1) : 0 ----------------
__global__ __launch_bounds__(TPB) void k_mark1(
    const unsigned* __restrict__ ukey, const float* __restrict__ s1,
    const float* __restrict__ h1p, float* __restrict__ z1,
    unsigned char* __restrict__ keep, unsigned* __restrict__ ctrl, int N)
{
  int i = blockIdx.x*TPB + threadIdx.x;
  if (i >= N) return;
  unsigned u = ukey[i], T = ctrl[3], needT = ctrl[4];
  bool sel = u > T;
  if (!sel && u == T) sel = (atomicAdd(&ctrl[5], 1u) < needT);
  keep[i] = sel ? (unsigned char)1 : (unsigned char)0;
  float tv = sel ? tanhf(s1[i]) : 0.0f;
  const float4* hp = (const float4*)(h1p + (size_t)i*16);
  float4* zp = (float4*)(z1 + (size_t)i*16);
  #pragma unroll
  for (int q=0;q<4;++q){
    float4 v = hp[q];
    zp[q] = make_float4(v.x*tv, v.y*tv, v.z*tv, v.w*tv);
  }
}

// ---------------- conv2 epilogue: reduce partials + GEMM 16->32 + BN stats ----------------
__global__ __launch_bounds__(TPB) void k_conv2post(
    const float* __restrict__ partial, const unsigned char* __restrict__ keep,
    const float* __restrict__ W2, float* __restrict__ h2, int N,
    float* __restrict__ stats)
{
  __shared__ float W2s[512];
  __shared__ float red[TPB][33];
  for (int i = threadIdx.x; i < 512; i += TPB) W2s[i] = W2[i];
  __syncthreads();
  int i = blockIdx.x*TPB + threadIdx.x;
  float h[32];
  #pragma unroll
  for (int c2=0;c2<32;++c2) h[c2]=0.f;
  bool act = (i < N) && keep[i];
  if (act){
    const float4* p0 = (const float4*)(partial + (size_t)i*16);
    const float4* p1 = (const float4*)(partial + ((size_t)N + i)*16);
    float a[16];
    #pragma unroll
    for (int k=0;k<4;++k){
      float4 av = p0[k], bv = p1[k];
      a[k*4+0]=av.x+bv.x; a[k*4+1]=av.y+bv.y; a[k*4+2]=av.z+bv.z; a[k*4+3]=av.w+bv.w;
    }
    #pragma unroll
    for (int c=0;c<16;++c){
      float av = a[c];
      const float* wrow = &W2s[c*32];
      #pragma unroll
      for (int c2=0;c2<32;++c2) h[c2] += av*wrow[c2];
    }
    float4* op = (float4*)(h2 + (size_t)i*32);
    #pragma unroll
    for (int q=0;q<8;++q)
      op[q] = make_float4(h[q*4+0],h[q*4+1],h[q*4+2],h[q*4+3]);
  }
  #pragma unroll
  for (int c2=0;c2<32;++c2) red[threadIdx.x][c2]=h[c2];
  __syncthreads();
  if (threadIdx.x < 64){
    int c = threadIdx.x & 31, r0 = (threadIdx.x>>5)*128;
    float sm=0.f, qs=0.f;
    for (int r=0;r<128;++r){ float v = red[r0+r][c]; sm+=v; qs+=v*v; }
    atomicAdd(&stats[c], sm);
    atomicAdd(&stats[32+c], qs);
  }
}

// ---------------- BN2 + lrelu (kept rows) + p2, s2; zero p/s for dropped ----------------
__global__ __launch_bounds__(TPB) void k_bn2(
    float* __restrict__ h, const float* __restrict__ stats,
    const float* __restrict__ g, const float* __restrict__ be,
    const float* __restrict__ Wr, const float* __restrict__ br,
    const float* __restrict__ Wroot, const unsigned char* __restrict__ keep,
    float* __restrict__ p, float* __restrict__ s, int N, float invn)
{
  int i = blockIdx.x*TPB + threadIdx.x;
  if (i >= N) return;
  if (!keep[i]){ p[i] = 0.f; s[i] = 0.f; return; }
  float* hp = h + (size_t)i*32;
  float pv=0.f, rv=0.f;
  #pragma unroll
  for (int c=0;c<32;++c){
    float mu = stats[c]*invn;
    float var = stats[32+c]*invn - mu*mu;
    float rsd = 1.0f / sqrtf(var + 1e-5f);
    float v = (hp[c]-mu)*rsd*g[c] + be[c];
    v = lrelu(v);
    hp[c] = v;
    pv += v*Wr[c];
    rv += v*Wroot[c];
  }
  p[i] = pv;
  s[i] = rv + br[0];
}

// ---------------- final: select top-k2, pooled += h2p * tanh(s2) ----------------
__global__ __launch_bounds__(TPB) void k_final(
    const unsigned* __restrict__ ukey, const float* __restrict__ s2,
    const float* __restrict__ h2p, unsigned* __restrict__ ctrl,
    float* __restrict__ pooled, int N)
{
  __shared__ float red[TPB][33];
  int i = blockIdx.x*TPB + threadIdx.x;
  float contrib[32];
  #pragma unroll
  for (int c=0;c<32;++c) contrib[c]=0.f;
  if (i < N){
    unsigned u = ukey[i], T = ctrl[3], needT = ctrl[4];
    bool sel = u > T;
    if (!sel && u == T) sel = (atomicAdd(&ctrl[5], 1u) < needT);
    if (sel){
      float tv = tanhf(s2[i]);
      const float* hp = h2p + (size_t)i*32;
      #pragma unroll
      for (int c=0;c<32;++c) contrib[c] = hp[c]*tv;
    }
  }
  #pragma unroll
  for (int c=0;c<32;++c) red[threadIdx.x][c]=contrib[c];
  __syncthreads();
  if (threadIdx.x < 64){
    int c = threadIdx.x & 31, r0 = (threadIdx.x>>5)*128;
    float sm=0.f;
    for (int r=0;r<128;++r) sm += red[r0+r][c];
    atomicAdd(&pooled[c], sm);
  }
}

// ---------------- tiny MLP 32->8->4->2 ----------------
__global__ void k_mlp(const float* __restrict__ pooled,
    const float* __restrict__ fw1, const float* __restrict__ fb1,
    const float* __restrict__ fw2, const float* __restrict__ fb2,
    const float* __restrict__ fw3, const float* __restrict__ fb3,
    float* __restrict__ out)
{
  if (blockIdx.x==0 && threadIdx.x==0){
    float a[8];
    for (int o=0;o<8;++o){
      float t = fb1[o];
      for (int c=0;c<32;++c) t += pooled[c]*fw1[c*8+o];
      a[o] = lrelu(t);
    }
    float b[4];
    for (int o=0;o<4;++o){
      float t = fb2[o];
      for (int c=0;c<8;++c) t += a[c]*fw2[c*4+o];
      b[o] = lrelu(t);
    }
    for (int o=0;o<2;++o){
      float t = fb3[o];
      for (int c=0;c<4;++c) t += b[c]*fw3[c*2+o];
      out[o] = lrelu(t);
    }
  }
}

extern "C" void kernel_launch(void* const* d_in, const int* in_sizes, int n_in,
                              void* d_out, int out_size, void* d_ws, size_t ws_size,
                              hipStream_t stream)
{
  const float* x      = (const float*)d_in[0];
  const int*   ei     = (const int*)  d_in[1];
  // d_in[2] edge_weigth, d_in[3] batch: unused by the reference math
  const float* W1     = (const float*)d_in[4];
  const float* g1     = (const float*)d_in[6];
  const float* be1    = (const float*)d_in[7];
  const float* Wr1    = (const float*)d_in[8];
  const float* br1    = (const float*)d_in[9];
  const float* Wroot1 = (const float*)d_in[10];
  const float* W2     = (const float*)d_in[11];
  const float* g2     = (const float*)d_in[13];
  const float* be2    = (const float*)d_in[14];
  const float* Wr2    = (const float*)d_in[15];
  const float* br2    = (const float*)d_in[16];
  const float* Wroot2 = (const float*)d_in[17];
  const float* fw1    = (const float*)d_in[18];
  const float* fb1    = (const float*)d_in[19];
  const float* fw2    = (const float*)d_in[20];
  const float* fb2    = (const float*)d_in[21];
  const float* fw3    = (const float*)d_in[22];
  const float* fb3    = (const float*)d_in[23];

  int N = in_sizes[0] / 128;
  int E = in_sizes[1] / 2;
  const int* srcp = ei;
  const int* dstp = ei + E;
  int k1 = (N + 1) / 2;
  int k2 = (k1 + 1) / 2;
  int NB  = (N + 255) >> 8;           // 256-dst buckets (<= 1024)
  int nbN = (N + TPB - 1) / TPB;

  char* w = (char*)d_ws;
  size_t off = 0;
  auto alloc = [&](size_t bytes)->char* {
    char* ptr = w + off;
    off += (bytes + 255) & ~(size_t)255;
    return ptr;
  };
  // --- zeroed prefix: gcur | hist | ctrl(+stats+pooled) ---
  int*      gcur = (int*)     alloc(1024*4);
  unsigned* hist = (unsigned*)alloc(65536*4);
  unsigned* ctrl = (unsigned*)alloc(1024);
  size_t zerosz = off;
  float* stats1 = (float*)(ctrl + 32);   // 32 floats
  float* stats2 = (float*)(ctrl + 96);   // 64 floats
  float* pooled = (float*)(ctrl + 160);  // 32 floats
  // --- rest of workspace ---
  // agg1 (N*16) + aggB (N*16) are contiguous; h2 (N*32) overlays both
  // (agg1 dead after k_mark1, aggB never used standalone).
  float*    agg1    = (float*)   alloc((size_t)N*16*4);
  float*    aggB    = (float*)   alloc((size_t)N*16*4); (void)aggB;
  float*    h2      = agg1;
  float*    partial = (float*)   alloc((size_t)2*N*16*4); // 2 split partials
  unsigned* col     = (unsigned*)alloc((size_t)NB*BCAP*4);
  float*    h1      = (float*)   alloc((size_t)N*16*4);   // later reused as z1
  float*    sbuf    = (float*)   alloc((size_t)N*4);      // s1 then s2
  float*    pbuf    = (float*)   alloc((size_t)N*4);      // p1 then p2
  unsigned* ukey    = (unsigned*)alloc((size_t)N*4);
  unsigned char* keep = (unsigned char*)alloc((size_t)N);
  unsigned* cand    = (unsigned*)alloc((size_t)CAND_CAP*4);
  (void)ws_size; (void)n_in; (void)out_size;

  hipMemsetAsync(d_ws, 0, zerosz, stream);

  // layer 1
  k_gemm1     <<<(N + 2*TPB - 1)/(2*TPB), TPB, 0, stream>>>(x, W1, h1, N);
  k_bin       <<<BIN_BLOCKS, TPB, 0, stream>>>(srcp, dstp, E, NB, gcur, col);
  k_gagg      <<<NB*SPLIT, TPB, 0, stream>>>(h1, col, gcur, partial, N);
  k_red1      <<<nbN, TPB, 0, stream>>>(partial, agg1, stats1, N);
  k_bn1       <<<nbN, TPB, 0, stream>>>(agg1, stats1, g1, be1, Wr1, br1, Wroot1,
                                        pbuf, sbuf, N, 1.0f/(float)N);
  k_score     <<<NB*SPLIT, TPB, 0, stream>>>(pbuf, col, gcur, sbuf, N);
  // SAG pool 1 (radix select k1)
  k_keyhist   <<<nbN, TPB, 0, stream>>>(sbuf, nullptr, ukey, hist, N);
  k_findbucket<<<1, TPB, 0, stream>>>(hist, (unsigned)k1, ctrl);
  k_collect   <<<nbN, TPB, 0, stream>>>(ukey, cand, ctrl, hist, N);
  k_refine    <<<1, TPB, 0, stream>>>(cand, ctrl);
  k_mark1     <<<nbN, TPB, 0, stream>>>(ukey, sbuf, agg1, h1, keep, ctrl, N);
  // layer 2 (z1 rows of dropped nodes are exact zeros -> unconditional gathers)
  k_gagg      <<<NB*SPLIT, TPB, 0, stream>>>(h1, col, gcur, partial, N);
  k_conv2post <<<nbN, TPB, 0, stream>>>(partial, keep, W2, h2, N, stats2);
  k_bn2       <<<nbN, TPB, 0, stream>>>(h2, stats2, g2, be2, Wr2, br2, Wroot2, keep,
                                        pbuf, sbuf, N, 1.0f/(float)k1);
  k_score     <<<NB*SPLIT, TPB, 0, stream>>>(pbuf, col, gcur, sbuf, N);
  // SAG pool 2 (radix select k2) + global pool
  k_keyhist   <<<nbN, TPB, 0, stream>>>(sbuf, keep, ukey, hist, N);
  k_findbucket<<<1, TPB, 0, stream>>>(hist, (unsigned)k2, ctrl);
  k_collect   <<<nbN, TPB, 0, stream>>>(ukey, cand, ctrl, hist, N);
  k_refine    <<<1, TPB, 0, stream>>>(cand, ctrl);
  k_final     <<<nbN, TPB, 0, stream>>>(ukey, sbuf, h2, ctrl, pooled, N);
  k_mlp       <<<1, 64, 0, stream>>>(pooled, fw1, fb1, fw2, fb2, fw3, fb3, (float*)d_out);
}

// Round 7
// 1270.103 us; speedup vs baseline: 1.9217x; 1.7486x over previous
//
#include <hip/hip_runtime.h>
#include <math.h>

#define TPB 256
#define CAND_CAP 262144u
#define BCAP 9216      // slots per 256-dst bucket: mean 8184, +11 sigma (mult of 8)
#define SPLIT 2        // blocks per bucket in gather kernels
#define BIN_BLOCKS 512

__device__ __forceinline__ float lrelu(float v){ return v >= 0.0f ? v : 0.01f*v; }
__device__ __forceinline__ unsigned fkey(float f){
  unsigned b = __float_as_uint(f);
  return (b & 0x80000000u) ? ~b : (b | 0x80000000u);
}

// ---------------- gemm1: h1 = x @ W1 (128->16) ----------------
__global__ __launch_bounds__(TPB) void k_gemm1(
    const float* __restrict__ x, const float* __restrict__ W1,
    float* __restrict__ h1, int N)
{
  __shared__ float Ws[2048]; // transposed: Ws[c*128+k]
  for (int idx = threadIdx.x; idx < 2048; idx += TPB){
    int k = idx >> 4, c = idx & 15;
    Ws[c*128 + k] = W1[idx];
  }
  __syncthreads();
  int base = blockIdx.x*(2*TPB) + threadIdx.x;
  int nn[2]; bool val[2];
  #pragma unroll
  for (int j=0;j<2;++j){ nn[j] = base + j*TPB; val[j] = nn[j] < N; }
  float acc[2][16];
  #pragma unroll
  for (int j=0;j<2;++j)
    #pragma unroll
    for (int c=0;c<16;++c) acc[j][c]=0.f;
  for (int k4=0;k4<32;++k4){
    float4 xv[2];
    #pragma unroll
    for (int j=0;j<2;++j)
      xv[j] = val[j] ? ((const float4*)(x + (size_t)nn[j]*128))[k4] : make_float4(0.f,0.f,0.f,0.f);
    #pragma unroll
    for (int c=0;c<16;++c){
      float4 wv = *(const float4*)&Ws[c*128 + k4*4];
      #pragma unroll
      for (int j=0;j<2;++j)
        acc[j][c] += xv[j].x*wv.x + xv[j].y*wv.y + xv[j].z*wv.z + xv[j].w*wv.w;
    }
  }
  #pragma unroll
  for (int j=0;j<2;++j) if (val[j]){
    float4* op = (float4*)(h1 + (size_t)nn[j]*16);
    #pragma unroll
    for (int q=0;q<4;++q)
      op[q] = make_float4(acc[j][q*4+0],acc[j][q*4+1],acc[j][q*4+2],acc[j][q*4+3]);
  }
}

// ---------------- bin edges into 256-dst buckets, packed (dst&255)<<24 | src ----------
__global__ __launch_bounds__(TPB) void k_bin(
    const int* __restrict__ src, const int* __restrict__ dst, int E,
    int NB, int* __restrict__ gcur, unsigned* __restrict__ col)
{
  __shared__ int histL[1024];
  int chunk = (E + gridDim.x - 1) / gridDim.x;
  int e0 = blockIdx.x*chunk;
  int e1 = e0 + chunk; if (e1 > E) e1 = E;
  for (int i = threadIdx.x; i < 1024; i += TPB) histL[i] = 0;
  __syncthreads();
  for (int e = e0 + threadIdx.x; e < e1; e += TPB)
    atomicAdd(&histL[dst[e] >> 8], 1);
  __syncthreads();
  for (int b = threadIdx.x; b < 1024; b += TPB){
    int c = histL[b];
    histL[b] = (c > 0) ? atomicAdd(&gcur[b], c) : 0;
  }
  __syncthreads();
  for (int e = e0 + threadIdx.x; e < e1; e += TPB){
    int d = dst[e];
    int b = d >> 8;
    int slot = atomicAdd(&histL[b], 1);
    if (slot < BCAP)
      col[(size_t)b*BCAP + slot] = ((unsigned)(d & 255) << 24) | (unsigned)src[e];
  }
}

// ---------------- sort each bucket by dl (LDS counting sort, in place) ----------------
__global__ __launch_bounds__(TPB) void k_sort(
    unsigned* __restrict__ col, const int* __restrict__ gcur)
{
  __shared__ unsigned stage[BCAP];   // 36 KB
  __shared__ unsigned hist[256];
  __shared__ unsigned scan[256];
  __shared__ unsigned curs[256];
  int b = blockIdx.x;
  int len = gcur[b]; if (len > BCAP) len = BCAP;
  unsigned* ce = col + (size_t)b*BCAP;
  int t = threadIdx.x;
  hist[t] = 0u;
  __syncthreads();
  for (int e = t; e < len; e += TPB){
    unsigned pk = ce[e];
    stage[e] = pk;
    atomicAdd(&hist[pk>>24], 1u);
  }
  __syncthreads();
  scan[t] = hist[t];
  __syncthreads();
  for (int o = 1; o < 256; o <<= 1){
    unsigned a = (t >= o) ? scan[t-o] : 0u;
    __syncthreads();
    scan[t] += a;
    __syncthreads();
  }
  curs[t] = scan[t] - hist[t];  // exclusive prefix
  __syncthreads();
  for (int e = t; e < len; e += TPB){
    unsigned pk = stage[e];
    unsigned pos = atomicAdd(&curs[pk>>24], 1u);
    ce[pos] = pk;
  }
}

// ---------------- gather-aggregate on dl-SORTED buckets: register run accumulation -------
// ~0.17 LDS atomics/edge (flush at run boundaries only). SPLIT blocks/bucket;
// partial[s] rows owned exclusively by split s -> plain stores.
__global__ __launch_bounds__(TPB) void k_gagg(
    const float* __restrict__ feat, const unsigned* __restrict__ col,
    const int* __restrict__ gcur, float* __restrict__ partial, int N)
{
  __shared__ float acc[256*17];   // acc[dl*17 + ch]
  int b = blockIdx.x >> 1, s = blockIdx.x & 1;
  for (int i = threadIdx.x; i < 256*17; i += TPB) acc[i] = 0.f;
  __syncthreads();
  int len = gcur[b]; if (len > BCAP) len = BCAP;
  int half = (len + 1) >> 1;
  int e0b = s*half;
  int e1b = e0b + half; if (e1b > len) e1b = len;
  int hl = e1b - e0b;
  const unsigned* ce = col + (size_t)b*BCAP;
  int q = threadIdx.x & 3, le = threadIdx.x >> 2, c0 = q*4;
  if (hl > 0){
    int C = (hl + 63) >> 6;          // edges per 4-lane group (contiguous chunk)
    int gs = e0b + le*C;
    int ge = gs + C; if (ge > e1b) ge = e1b;
    int wbase = (threadIdx.x & 63) & ~3;   // quad base lane within wave
    int cur_dl = -1;
    float ax=0.f, ay=0.f, az=0.f, aw=0.f;
    for (int e0 = gs; e0 < ge; e0 += 8){
      int i0 = e0 + q;     if (i0 >= ge) i0 = ge-1;
      int i1 = e0 + 4 + q; if (i1 >= ge) i1 = ge-1;
      unsigned k0 = ce[i0], k1 = ce[i1];
      unsigned pk[8];
      #pragma unroll
      for (int jj=0;jj<4;++jj){
        pk[jj]   = __shfl(k0, wbase+jj, 64);
        pk[4+jj] = __shfl(k1, wbase+jj, 64);
      }
      float4 v[8];
      #pragma unroll
      for (int j=0;j<8;++j)
        v[j] = ((const float4*)(feat + (size_t)(pk[j] & 0xFFFFFFu)*16))[q];
      #pragma unroll
      for (int j=0;j<8;++j){
        if (e0 + j < ge){
          int dl = (int)(pk[j] >> 24);
          if (dl != cur_dl){
            if (cur_dl >= 0){
              float* ap = &acc[cur_dl*17 + c0];
              atomicAdd(ap+0, ax); atomicAdd(ap+1, ay);
              atomicAdd(ap+2, az); atomicAdd(ap+3, aw);
            }
            cur_dl = dl; ax=v[j].x; ay=v[j].y; az=v[j].z; aw=v[j].w;
          } else {
            ax+=v[j].x; ay+=v[j].y; az+=v[j].z; aw+=v[j].w;
          }
        }
      }
    }
    if (cur_dl >= 0){
      float* ap = &acc[cur_dl*17 + c0];
      atomicAdd(ap+0, ax); atomicAdd(ap+1, ay);
      atomicAdd(ap+2, az); atomicAdd(ap+3, aw);
    }
  }
  __syncthreads();
  int t = threadIdx.x;
  int d = b*256 + t;
  if (d < N){
    float4* pp = (float4*)(partial + ((size_t)s*N + d)*16);
    #pragma unroll
    for (int k=0;k<4;++k)
      pp[k] = make_float4(acc[t*17+k*4+0], acc[t*17+k*4+1],
                          acc[t*17+k*4+2], acc[t*17+k*4+3]);
  }
}

// ---------------- reduce partials -> agg1 + BN stats ----------------
__global__ __launch_bounds__(TPB) void k_red1(
    const float* __restrict__ partial, float* __restrict__ agg,
    float* __restrict__ stats, int N)
{
  __shared__ float red[TPB][17];
  int i = blockIdx.x*TPB + threadIdx.x;
  float v[16];
  if (i < N){
    const float4* p0 = (const float4*)(partial + (size_t)i*16);
    const float4* p1 = (const float4*)(partial + ((size_t)N + i)*16);
    float4* op = (float4*)(agg + (size_t)i*16);
    #pragma unroll
    for (int k=0;k<4;++k){
      float4 a = p0[k], bq = p1[k];
      float4 r = make_float4(a.x+bq.x, a.y+bq.y, a.z+bq.z, a.w+bq.w);
      op[k] = r;
      v[k*4+0]=r.x; v[k*4+1]=r.y; v[k*4+2]=r.z; v[k*4+3]=r.w;
    }
  } else {
    #pragma unroll
    for (int c=0;c<16;++c) v[c]=0.f;
  }
  #pragma unroll
  for (int c=0;c<16;++c) red[threadIdx.x][c]=v[c];
  __syncthreads();
  if (threadIdx.x < 32){
    int c = threadIdx.x & 15, r0 = (threadIdx.x>>4)*128;
    float sm=0.f, qs=0.f;
    for (int r=0;r<128;++r){ float vv = red[r0+r][c]; sm+=vv; qs+=vv*vv; }
    atomicAdd(&stats[c], sm);
    atomicAdd(&stats[16+c], qs);
  }
}

// ---------------- BN1 + lrelu (in place) + p1 = h.Wrel, s1 = h.Wroot + br ----------------
__global__ __launch_bounds__(TPB) void k_bn1(
    float* __restrict__ h, const float* __restrict__ stats,
    const float* __restrict__ g, const float* __restrict__ be,
    const float* __restrict__ Wr, const float* __restrict__ br,
    const float* __restrict__ Wroot,
    float* __restrict__ p, float* __restrict__ s, int N, float invn)
{
  int i = blockIdx.x*TPB + threadIdx.x;
  if (i >= N) return;
  float* hp = h + (size_t)i*16;
  float pv=0.f, rv=0.f;
  #pragma unroll
  for (int c=0;c<16;++c){
    float mu = stats[c]*invn;
    float var = stats[16+c]*invn - mu*mu;
    float rsd = 1.0f / sqrtf(var + 1e-5f);
    float v = (hp[c]-mu)*rsd*g[c] + be[c];
    v = lrelu(v);
    hp[c] = v;
    pv += v*Wr[c];
    rv += v*Wroot[c];
  }
  p[i] = pv;
  s[i] = rv + br[0];
}

// ---------------- score aggregation: SPLIT blocks/bucket, 8-batched, atomic flush ---------
// layer 2 needs no mask: bn2 zeroes p for dropped nodes; dropped dst rows masked at keyhist.
__global__ __launch_bounds__(TPB) void k_score(
    const float* __restrict__ p, const unsigned* __restrict__ col,
    const int* __restrict__ gcur, float* __restrict__ s, int N)
{
  __shared__ float sacc[256];
  int b = blockIdx.x >> 1;
  int sp = blockIdx.x & 1;
  sacc[threadIdx.x] = 0.f;
  __syncthreads();
  int len = gcur[b]; if (len > BCAP) len = BCAP;
  int ch = (((len + 1) >> 1) + 7) & ~7;
  int e0b = sp*ch;
  int e1b = e0b + ch; if (e1b > len) e1b = len;
  const unsigned* ce = col + (size_t)b*BCAP;
  for (int e0 = e0b + threadIdx.x*8; e0 < e1b; e0 += TPB*8){
    uint4 u0 = *(const uint4*)(ce + e0);
    uint4 u1 = *(const uint4*)(ce + e0 + 4);
    unsigned pk[8] = {u0.x,u0.y,u0.z,u0.w,u1.x,u1.y,u1.z,u1.w};
    int cnt = e1b - e0; // >= 1
    float pv[8];
    #pragma unroll
    for (int j=0;j<8;++j){
      int si = (int)(pk[j] & 0xFFFFFFu);
      if (si >= N) si = 0;   // stale-slot guard beyond len
      pv[j] = p[si];
    }
    // sorted buckets -> consecutive pk share dl; run-accumulate to cut LDS atomics
    float run = 0.f; int cur = -1;
    #pragma unroll
    for (int j=0;j<8;++j){
      if (j < cnt){
        int dl = (int)(pk[j] >> 24);
        if (dl != cur){
          if (cur >= 0) atomicAdd(&sacc[cur], run);
          cur = dl; run = pv[j];
        } else run += pv[j];
      }
    }
    if (cur >= 0) atomicAdd(&sacc[cur], run);
  }
  __syncthreads();
  int d = b*256 + threadIdx.x;
  if (d < N && sacc[threadIdx.x] != 0.f) atomicAdd(&s[d], sacc[threadIdx.x]);
}

// ---------------- radix-select stage 1: monotonic keys + top-16-bit histogram ----------------
__global__ __launch_bounds__(TPB) void k_keyhist(
    const float* __restrict__ s, const unsigned char* __restrict__ keep,
    unsigned* __restrict__ ukey, unsigned* __restrict__ hist, int N)
{
  int i = blockIdx.x*TPB + threadIdx.x;
  if (i >= N) return;
  unsigned u = 0u;
  if (!keep || keep[i]) u = fkey(s[i]);
  ukey[i] = u;
  if (u) atomicAdd(&hist[u>>16], 1u);
}

// ---------------- find threshold bucket (1 block) ----------------
__global__ __launch_bounds__(TPB) void k_findbucket(
    const unsigned* __restrict__ hist, unsigned k, unsigned* __restrict__ ctrl)
{
  __shared__ unsigned seg[TPB];
  __shared__ unsigned hb[256];
  __shared__ unsigned sS, scum;
  unsigned t = threadIdx.x;
  const uint4* h4 = (const uint4*)hist;
  unsigned ssum = 0;
  for (int q=0;q<64;++q){
    uint4 v = h4[t*64 + q];
    ssum += v.x + v.y + v.z + v.w;
  }
  seg[t] = ssum;
  __syncthreads();
  if (t == 0){
    unsigned cum = 0, S = 255;
    for (int s2=255; s2>=0; --s2){
      if (cum + seg[s2] >= k){ S = (unsigned)s2; break; }
      cum += seg[s2];
    }
    sS = S; scum = cum;
  }
  __syncthreads();
  hb[t] = hist[sS*256 + t];
  __syncthreads();
  if (t == 0){
    unsigned cum = scum, B = 0, need = 0;
    for (int b=255;b>=0;--b){
      unsigned h = hb[b];
      if (cum + h >= k){ B = sS*256 + (unsigned)b; need = k - cum; break; }
      cum += h;
    }
    ctrl[1] = B;
    ctrl[2] = need;
  }
}

// ---------------- collect boundary-bucket candidates; also re-zero hist for next use --------
__global__ __launch_bounds__(TPB) void k_collect(
    const unsigned* __restrict__ ukey, unsigned* __restrict__ cand,
    unsigned* __restrict__ ctrl, unsigned* __restrict__ hist, int N)
{
  int i = blockIdx.x*TPB + threadIdx.x;
  if (i < 65536) hist[i] = 0u;
  if (i < N){
    unsigned u = ukey[i];
    if ((u>>16) == ctrl[1]){
      unsigned pos = atomicAdd(&ctrl[6], 1u);
      if (pos < CAND_CAP) cand[pos] = u;
    }
  }
}

// ---------------- refine low 16 bits (1 block) -> T, needT; resets tie & cand counters ------
__global__ __launch_bounds__(TPB) void k_refine(
    const unsigned* __restrict__ cand, unsigned* __restrict__ ctrl)
{
  __shared__ unsigned h8[256];
  __shared__ unsigned sB2, sN2;
  unsigned t = threadIdx.x;
  unsigned L = ctrl[6];
  unsigned need = ctrl[2];
  h8[t] = 0u; __syncthreads();
  for (unsigned i=t; i<L; i+=TPB) atomicAdd(&h8[(cand[i]>>8)&0xFFu], 1u);
  __syncthreads();
  if (t == 0){
    unsigned cum=0, B2=0, n2=need;
    for (int b=255;b>=0;--b){
      unsigned h = h8[b];
      if (cum + h >= need){ B2=(unsigned)b; n2 = need - cum; break; }
      cum += h;
    }
    sB2 = B2; sN2 = n2;
  }
  __syncthreads();
  unsigned B2 = sB2, need2 = sN2;
  h8[t] = 0u; __syncthreads();
  for (unsigned i=t; i<L; i+=TPB){
    unsigned u = cand[i];
    if (((u>>8)&0xFFu) == B2) atomicAdd(&h8[u&0xFFu], 1u);
  }
  __syncthreads();
  if (t == 0){
    unsigned cum=0, B3=0, n3=need2;
    for (int b=255;b>=0;--b){
      unsigned h = h8[b];
      if (cum + h >= need2){ B3=(unsigned)b; n3 = need2 - cum; break; }
      cum += h;
    }
    unsigned B = ctrl[1];
    ctrl[3] = (B<<16) | (B2<<8) | B3; // threshold key T
    ctrl[4] = n3;                    // how many ==T to take
    ctrl[5] = 0u;                    // tie counter
    ctrl[6] = 0u;                    // cand counter (for next selection)
  }
}

// ---------------- mark keep1 + z1 = keep ? h1p * tanh(s1) : 0 ----------------
__global__ __launch_bounds__(TPB) void k_mark1(
    const unsigned* __restrict__ ukey, const float* __restrict__ s1,
    const float* __restrict__ h1p, float* __restrict__ z1,
    unsigned char* __restrict__ keep, unsigned* __restrict__ ctrl, int N)
{
  int i = blockIdx.x*TPB + threadIdx.x;
  if (i >= N) return;
  unsigned u = ukey[i], T = ctrl[3], needT = ctrl[4];
  bool sel = u > T;
  if (!sel && u == T) sel = (atomicAdd(&ctrl[5], 1u) < needT);
  keep[i] = sel ? (unsigned char)1 : (unsigned char)0;
  float tv = sel ? tanhf(s1[i]) : 0.0f;
  const float4* hp = (const float4*)(h1p + (size_t)i*16);
  float4* zp = (float4*)(z1 + (size_t)i*16);
  #pragma unroll
  for (int q=0;q<4;++q){
    float4 v = hp[q];
    zp[q] = make_float4(v.x*tv, v.y*tv, v.z*tv, v.w*tv);
  }
}

// ---------------- conv2 epilogue: reduce partials + GEMM 16->32 + BN stats ----------------
__global__ __launch_bounds__(TPB) void k_conv2post(
    const float* __restrict__ partial, const unsigned char* __restrict__ keep,
    const float* __restrict__ W2, float* __restrict__ h2, int N,
    float* __restrict__ stats)
{
  __shared__ float W2s[512];
  __shared__ float red[TPB][33];
  for (int i = threadIdx.x; i < 512; i += TPB) W2s[i] = W2[i];
  __syncthreads();
  int i = blockIdx.x*TPB + threadIdx.x;
  float h[32];
  #pragma unroll
  for (int c2=0;c2<32;++c2) h[c2]=0.f;
  bool act = (i < N) && keep[i];
  if (act){
    const float4* p0 = (const float4*)(partial + (size_t)i*16);
    const float4* p1 = (const float4*)(partial + ((size_t)N + i)*16);
    float a[16];
    #pragma unroll
    for (int k=0;k<4;++k){
      float4 av = p0[k], bv = p1[k];
      a[k*4+0]=av.x+bv.x; a[k*4+1]=av.y+bv.y; a[k*4+2]=av.z+bv.z; a[k*4+3]=av.w+bv.w;
    }
    #pragma unroll
    for (int c=0;c<16;++c){
      float av = a[c];
      const float* wrow = &W2s[c*32];
      #pragma unroll
      for (int c2=0;c2<32;++c2) h[c2] += av*wrow[c2];
    }
    float4* op = (float4*)(h2 + (size_t)i*32);
    #pragma unroll
    for (int q=0;q<8;++q)
      op[q] = make_float4(h[q*4+0],h[q*4+1],h[q*4+2],h[q*4+3]);
  }
  #pragma unroll
  for (int c2=0;c2<32;++c2) red[threadIdx.x][c2]=h[c2];
  __syncthreads();
  if (threadIdx.x < 64){
    int c = threadIdx.x & 31, r0 = (threadIdx.x>>5)*128;
    float sm=0.f, qs=0.f;
    for (int r=0;r<128;++r){ float v = red[r0+r][c]; sm+=v; qs+=v*v; }
    atomicAdd(&stats[c], sm);
    atomicAdd(&stats[32+c], qs);
  }
}

// ---------------- BN2 + lrelu (kept rows) + p2, s2; zero p/s for dropped ----------------
__global__ __launch_bounds__(TPB) void k_bn2(
    float* __restrict__ h, const float* __restrict__ stats,
    const float* __restrict__ g, const float* __restrict__ be,
    const float* __restrict__ Wr, const float* __restrict__ br,
    const float* __restrict__ Wroot, const unsigned char* __restrict__ keep,
    float* __restrict__ p, float* __restrict__ s, int N, float invn)
{
  int i = blockIdx.x*TPB + threadIdx.x;
  if (i >= N) return;
  if (!keep[i]){ p[i] = 0.f; s[i] = 0.f; return; }
  float* hp = h + (size_t)i*32;
  float pv=0.f, rv=0.f;
  #pragma unroll
  for (int c=0;c<32;++c){
    float mu = stats[c]*invn;
    float var = stats[32+c]*invn - mu*mu;
    float rsd = 1.0f / sqrtf(var + 1e-5f);
    float v = (hp[c]-mu)*rsd*g[c] + be[c];
    v = lrelu(v);
    hp[c] = v;
    pv += v*Wr[c];
    rv += v*Wroot[c];
  }
  p[i] = pv;
  s[i] = rv + br[0];
}

// ---------------- final: select top-k2, pooled += h2p * tanh(s2) ----------------
__global__ __launch_bounds__(TPB) void k_final(
    const unsigned* __restrict__ ukey, const float* __restrict__ s2,
    const float* __restrict__ h2p, unsigned* __restrict__ ctrl,
    float* __restrict__ pooled, int N)
{
  __shared__ float red[TPB][33];
  int i = blockIdx.x*TPB + threadIdx.x;
  float contrib[32];
  #pragma unroll
  for (int c=0;c<32;++c) contrib[c]=0.f;
  if (i < N){
    unsigned u = ukey[i], T = ctrl[3], needT = ctrl[4];
    bool sel = u > T;
    if (!sel && u == T) sel = (atomicAdd(&ctrl[5], 1u) < needT);
    if (sel){
      float tv = tanhf(s2[i]);
      const float* hp = h2p + (size_t)i*32;
      #pragma unroll
      for (int c=0;c<32;++c) contrib[c] = hp[c]*tv;
    }
  }
  #pragma unroll
  for (int c=0;c<32;++c) red[threadIdx.x][c]=contrib[c];
  __syncthreads();
  if (threadIdx.x < 64){
    int c = threadIdx.x & 31, r0 = (threadIdx.x>>5)*128;
    float sm=0.f;
    for (int r=0;r<128;++r) sm += red[r0+r][c];
    atomicAdd(&pooled[c], sm);
  }
}

// ---------------- tiny MLP 32->8->4->2 ----------------
__global__ void k_mlp(const float* __restrict__ pooled,
    const float* __restrict__ fw1, const float* __restrict__ fb1,
    const float* __restrict__ fw2, const float* __restrict__ fb2,
    const float* __restrict__ fw3, const float* __restrict__ fb3,
    float* __restrict__ out)
{
  if (blockIdx.x==0 && threadIdx.x==0){
    float a[8];
    for (int o=0;o<8;++o){
      float t = fb1[o];
      for (int c=0;c<32;++c) t += pooled[c]*fw1[c*8+o];
      a[o] = lrelu(t);
    }
    float b[4];
    for (int o=0;o<4;++o){
      float t = fb2[o];
      for (int c=0;c<8;++c) t += a[c]*fw2[c*4+o];
      b[o] = lrelu(t);
    }
    for (int o=0;o<2;++o){
      float t = fb3[o];
      for (int c=0;c<4;++c) t += b[c]*fw3[c*2+o];
      out[o] = lrelu(t);
    }
  }
}

extern "C" void kernel_launch(void* const* d_in, const int* in_sizes, int n_in,
                              void* d_out, int out_size, void* d_ws, size_t ws_size,
                              hipStream_t stream)
{
  const float* x      = (const float*)d_in[0];
  const int*   ei     = (const int*)  d_in[1];
  // d_in[2] edge_weigth, d_in[3] batch: unused by the reference math
  const float* W1     = (const float*)d_in[4];
  const float* g1     = (const float*)d_in[6];
  const float* be1    = (const float*)d_in[7];
  const float* Wr1    = (const float*)d_in[8];
  const float* br1    = (const float*)d_in[9];
  const float* Wroot1 = (const float*)d_in[10];
  const float* W2     = (const float*)d_in[11];
  const float* g2     = (const float*)d_in[13];
  const float* be2    = (const float*)d_in[14];
  const float* Wr2    = (const float*)d_in[15];
  const float* br2    = (const float*)d_in[16];
  const float* Wroot2 = (const float*)d_in[17];
  const float* fw1    = (const float*)d_in[18];
  const float* fb1    = (const float*)d_in[19];
  const float* fw2    = (const float*)d_in[20];
  const float* fb2    = (const float*)d_in[21];
  const float* fw3    = (const float*)d_in[22];
  const float* fb3    = (const float*)d_in[23];

  int N = in_sizes[0] / 128;
  int E = in_sizes[1] / 2;
  const int* srcp = ei;
  const int* dstp = ei + E;
  int k1 = (N + 1) / 2;
  int k2 = (k1 + 1) / 2;
  int NB  = (N + 255) >> 8;           // 256-dst buckets (<= 1024)
  int nbN = (N + TPB - 1) / TPB;

  char* w = (char*)d_ws;
  size_t off = 0;
  auto alloc = [&](size_t bytes)->char* {
    char* ptr = w + off;
    off += (bytes + 255) & ~(size_t)255;
    return ptr;
  };
  // --- zeroed prefix: gcur | hist | ctrl(+stats+pooled) ---
  int*      gcur = (int*)     alloc(1024*4);
  unsigned* hist = (unsigned*)alloc(65536*4);
  unsigned* ctrl = (unsigned*)alloc(1024);
  size_t zerosz = off;
  float* stats1 = (float*)(ctrl + 32);   // 32 floats
  float* stats2 = (float*)(ctrl + 96);   // 64 floats
  float* pooled = (float*)(ctrl + 160);  // 32 floats
  // --- rest of workspace ---
  // agg1 (N*16) + aggB (N*16) are contiguous; h2 (N*32) overlays both
  // (agg1 dead after k_mark1, aggB never used standalone).
  float*    agg1    = (float*)   alloc((size_t)N*16*4);
  float*    aggB    = (float*)   alloc((size_t)N*16*4); (void)aggB;
  float*    h2      = agg1;
  float*    partial = (float*)   alloc((size_t)2*N*16*4); // 2 split partials
  unsigned* col     = (unsigned*)alloc((size_t)NB*BCAP*4);
  float*    h1      = (float*)   alloc((size_t)N*16*4);   // later reused as z1
  float*    sbuf    = (float*)   alloc((size_t)N*4);      // s1 then s2
  float*    pbuf    = (float*)   alloc((size_t)N*4);      // p1 then p2
  unsigned* ukey    = (unsigned*)alloc((size_t)N*4);
  unsigned char* keep = (unsigned char*)alloc((size_t)N);
  unsigned* cand    = (unsigned*)alloc((size_t)CAND_CAP*4);
  (void)ws_size; (void)n_in; (void)out_size;

  hipMemsetAsync(d_ws, 0, zerosz, stream);

  // layer 1
  k_gemm1     <<<(N + 2*TPB - 1)/(2*TPB), TPB, 0, stream>>>(x, W1, h1, N);
  k_bin       <<<BIN_BLOCKS, TPB, 0, stream>>>(srcp, dstp, E, NB, gcur, col);
  k_sort      <<<NB, TPB, 0, stream>>>(col, gcur);
  k_gagg      <<<NB*SPLIT, TPB, 0, stream>>>(h1, col, gcur, partial, N);
  k_red1      <<<nbN, TPB, 0, stream>>>(partial, agg1, stats1, N);
  k_bn1       <<<nbN, TPB, 0, stream>>>(agg1, stats1, g1, be1, Wr1, br1, Wroot1,
                                        pbuf, sbuf, N, 1.0f/(float)N);
  k_score     <<<NB*SPLIT, TPB, 0, stream>>>(pbuf, col, gcur, sbuf, N);
  // SAG pool 1 (radix select k1)
  k_keyhist   <<<nbN, TPB, 0, stream>>>(sbuf, nullptr, ukey, hist, N);
  k_findbucket<<<1, TPB, 0, stream>>>(hist, (unsigned)k1, ctrl);
  k_collect   <<<nbN, TPB, 0, stream>>>(ukey, cand, ctrl, hist, N);
  k_refine    <<<1, TPB, 0, stream>>>(cand, ctrl);
  k_mark1     <<<nbN, TPB, 0, stream>>>(ukey, sbuf, agg1, h1, keep, ctrl, N);
  // layer 2 (z1 rows of dropped nodes are exact zeros -> unconditional gathers)
  k_gagg      <<<NB*SPLIT, TPB, 0, stream>>>(h1, col, gcur, partial, N);
  k_conv2post <<<nbN, TPB, 0, stream>>>(partial, keep, W2, h2, N, stats2);
  k_bn2       <<<nbN, TPB, 0, stream>>>(h2, stats2, g2, be2, Wr2, br2, Wroot2, keep,
                                        pbuf, sbuf, N, 1.0f/(float)k1);
  k_score     <<<NB*SPLIT, TPB, 0, stream>>>(pbuf, col, gcur, sbuf, N);
  // SAG pool 2 (radix select k2) + global pool
  k_keyhist   <<<nbN, TPB, 0, stream>>>(sbuf, keep, ukey, hist, N);
  k_findbucket<<<1, TPB, 0, stream>>>(hist, (unsigned)k2, ctrl);
  k_collect   <<<nbN, TPB, 0, stream>>>(ukey, cand, ctrl, hist, N);
  k_refine    <<<1, TPB, 0, stream>>>(cand, ctrl);
  k_final     <<<nbN, TPB, 0, stream>>>(ukey, sbuf, h2, ctrl, pooled, N);
  k_mlp       <<<1, 64, 0, stream>>>(pooled, fw1, fb1, fw2, fb2, fw3, fb3, (float*)d_out);
}